// Round 1
// baseline (2426.308 us; speedup 1.0000x reference)
//
#include <hip/hip_runtime.h>
#include <hip/hip_bf16.h>
#include <cstdint>
#include <cstddef>

// ============================================================================
// SMoREGate on MI355X (gfx950)
//
// Pipeline (all sizes fixed: T=16384, D=2048, E=64, A=8):
//  1. memset zero region (Vt, norm2, imp, cnt)
//  2. split x  -> bf16 hi/mid/lo             (split-3 for fp32-grade MFMA)
//  3. split W1 -> bf16 hi/mid/lo
//  4. split W2 -> bf16 hi only               (GEMM2 only needs ~1e-3)
//  5. kn = l2норм(keys)                       (fp32)
//  6. Vt[e][k] = sum_j kn[e][j]*W2[j][k]     (fp32, j-split atomics)
//  7. c[e] = b2 . kn[e]
//  8. split Vt -> bf16 hi/mid/lo (padded to 128 rows, zeros)
//  9. GEMM1 (split-3, 6 products): h = relu(x@W1^T + b1), write h hi/mid/lo
// 10. GEMM2 (plain bf16): norm2[t] += (h@W2^T + b2)^2   (atomic, no p matrix)
// 11. rGEMM (split-3): r = h @ Vt^T  (M=16384,N=128,K=2048)
// 12. topk: logits = (r+c)/max(sqrt(norm2),1e-12); stable top-9; softmax top-8
// 13. balance loss (cv^2)
// 14. gather selected_keys = kn[idx]  (1.07 GB write)
//
// ws requirement ~449 MB.
// ============================================================================

typedef unsigned short ushort_t;
typedef __attribute__((ext_vector_type(8))) short short8;
typedef __attribute__((ext_vector_type(4))) float f32x4;
typedef __attribute__((ext_vector_type(4), aligned(4))) float f4u; // unaligned-ok float4

#define T_ROWS 16384
#define DIM 2048
#define NEXP 64

__device__ __forceinline__ unsigned short f2bf(float f){
  unsigned int u = __builtin_bit_cast(unsigned int, f);
  unsigned int r = (u + 0x7fffu + ((u >> 16) & 1u)) >> 16;
  return (unsigned short)r;
}
__device__ __forceinline__ float bf2f(unsigned short b){
  unsigned int u = ((unsigned int)b) << 16;
  return __builtin_bit_cast(float, u);
}

__device__ __forceinline__ void gload16(const void* g, void* l){
  __builtin_amdgcn_global_load_lds(
      (const __attribute__((address_space(1))) unsigned int*)g,
      (__attribute__((address_space(3))) unsigned int*)l, 16, 0, 0);
}

// ---------------------------------------------------------------------------
// split fp32 -> bf16 splits (NS=1: hi only; NS=3: hi/mid/lo)
// ---------------------------------------------------------------------------
template<int NS>
__global__ void split_kernel(const float* __restrict__ src, size_t n,
                             ushort_t* __restrict__ oh,
                             ushort_t* __restrict__ om,
                             ushort_t* __restrict__ ol){
  size_t i = ((size_t)blockIdx.x * blockDim.x + threadIdx.x) * 4;
  size_t stride = (size_t)gridDim.x * blockDim.x * 4;
  for (; i < n; i += stride){
    float4 v = *(const float4*)(src + i);
    float vv[4] = {v.x, v.y, v.z, v.w};
    ushort_t h[4], m[4], l[4];
    #pragma unroll
    for (int j = 0; j < 4; j++){
      float x = vv[j];
      unsigned short hb = f2bf(x);
      h[j] = hb;
      if (NS > 1){
        float r1 = x - bf2f(hb);
        unsigned short mb = f2bf(r1);
        m[j] = mb;
        float r2 = r1 - bf2f(mb);
        l[j] = f2bf(r2);
      }
    }
    *(ushort4*)(oh + i) = make_ushort4(h[0], h[1], h[2], h[3]);
    if (NS > 1){
      *(ushort4*)(om + i) = make_ushort4(m[0], m[1], m[2], m[3]);
      *(ushort4*)(ol + i) = make_ushort4(l[0], l[1], l[2], l[3]);
    }
  }
}

// ---------------------------------------------------------------------------
// kn = keys / max(||keys||, 1e-12), one block per expert
// ---------------------------------------------------------------------------
__global__ void knorm_kernel(const float* __restrict__ keys, float* __restrict__ kn){
  int e = blockIdx.x;
  int tid = threadIdx.x; // 256
  const float* src = keys + (size_t)e * DIM;
  float ss = 0.f;
  for (int i = tid; i < DIM; i += 256){ float v = src[i]; ss += v * v; }
  #pragma unroll
  for (int m = 1; m < 64; m <<= 1) ss += __shfl_xor(ss, m);
  __shared__ float red[4];
  int wid = tid >> 6, lane = tid & 63;
  if (lane == 0) red[wid] = ss;
  __syncthreads();
  float tot = red[0] + red[1] + red[2] + red[3];
  float inv = 1.0f / fmaxf(sqrtf(tot), 1e-12f);
  for (int i = tid; i < DIM; i += 256) kn[(size_t)e * DIM + i] = src[i] * inv;
}

// ---------------------------------------------------------------------------
// Vt[e][k] = sum_j kn[e][j] * W2[j][k]   (fp32, atomic accumulate, Vt zeroed)
// grid = 32 k-tiles x 8 j-splits = 256 blocks, 256 threads
// ---------------------------------------------------------------------------
__global__ void vt_kernel(const float* __restrict__ W2, const float* __restrict__ kn,
                          float* __restrict__ Vt){
  int tid = threadIdx.x;
  int kb = blockIdx.x & 31, js = blockIdx.x >> 5;
  int k0 = kb * 64, j0 = js * 256;
  __shared__ float w2s[32][64];
  __shared__ float kns[64][33];
  float acc[4][4];
  #pragma unroll
  for (int i = 0; i < 4; i++)
    #pragma unroll
    for (int m = 0; m < 4; m++) acc[i][m] = 0.f;
  int eg = tid >> 4, kg = tid & 15;
  for (int jc = 0; jc < 256; jc += 32){
    __syncthreads();
    #pragma unroll
    for (int p = 0; p < 8; p++){
      int el = p * 256 + tid;
      int jj = el >> 6, kk = el & 63;
      w2s[jj][kk] = W2[(size_t)(j0 + jc + jj) * DIM + k0 + kk];
      int e2 = el >> 5, j2 = el & 31;
      kns[e2][j2] = kn[(size_t)e2 * DIM + j0 + jc + j2];
    }
    __syncthreads();
    #pragma unroll
    for (int jj = 0; jj < 32; jj++){
      float4 w4 = *(float4*)&w2s[jj][kg * 4];
      float wv[4] = {w4.x, w4.y, w4.z, w4.w};
      #pragma unroll
      for (int i = 0; i < 4; i++){
        float kv = kns[eg * 4 + i][jj];
        #pragma unroll
        for (int m = 0; m < 4; m++) acc[i][m] += kv * wv[m];
      }
    }
  }
  #pragma unroll
  for (int i = 0; i < 4; i++)
    #pragma unroll
    for (int m = 0; m < 4; m++)
      atomicAdd(&Vt[(size_t)(eg * 4 + i) * DIM + k0 + kg * 4 + m], acc[i][m]);
}

// ---------------------------------------------------------------------------
// c[e] = b2 . kn[e], one wave per expert
// ---------------------------------------------------------------------------
__global__ void cvec_kernel(const float* __restrict__ b2, const float* __restrict__ kn,
                            float* __restrict__ c){
  int e = blockIdx.x;
  int lane = threadIdx.x; // 64
  float s = 0.f;
  for (int i = lane; i < DIM; i += 64) s += b2[i] * kn[(size_t)e * DIM + i];
  #pragma unroll
  for (int m = 1; m < 64; m <<= 1) s += __shfl_xor(s, m);
  if (lane == 0) c[e] = s;
}

// ---------------------------------------------------------------------------
// split-bf16 GEMM, C = A @ B^T, A:[M][K], B:[N][K], both bf16 splits.
// BM=BN=128, BK=32, 256 threads (4 waves 2x2), wave tile 64x64 (4x4 16x16 frags)
// SPLITS=3: 6 products (sa+sb<=2) -> ~fp32 accuracy.  SPLITS=1: plain bf16.
// LDS per tile [128 rows][4 slots of 16B], slot XOR-swizzled by (r^(r>>2))&3
// (applied on the global SOURCE so global_load_lds dest stays linear).
// ---------------------------------------------------------------------------
enum { EPI_H = 0, EPI_NORM = 1, EPI_F32 = 2 };

template<int SPLITS, int EPI>
__global__ __launch_bounds__(256) void gemm_bt(
    const ushort_t* __restrict__ A0, const ushort_t* __restrict__ A1, const ushort_t* __restrict__ A2,
    const ushort_t* __restrict__ B0, const ushort_t* __restrict__ B1, const ushort_t* __restrict__ B2,
    int M, int N, int K, int NB,
    const float* __restrict__ bias,
    float* __restrict__ outF,
    ushort_t* __restrict__ oh, ushort_t* __restrict__ om, ushort_t* __restrict__ ol)
{
  __shared__ ushort_t lds[SPLITS * 2 * 4096];
  const int tid = threadIdx.x;
  const int lane = tid & 63;
  const int wid = tid >> 6;
  const int wr = wid >> 1, wc = wid & 1;
  const int q = lane >> 4, lr = lane & 15;

  // bijective XCD swizzle (gridDim.x % 8 == 0 for all our launches)
  int nwg = gridDim.x;
  int bid = blockIdx.x;
  int wgid = (bid & 7) * (nwg >> 3) + (bid >> 3);
  int mblk = wgid / NB, nblk = wgid % NB;
  const int mrow0 = mblk * 128, ncol0 = nblk * 128;

  const ushort_t* Abase[3] = {A0, A1, A2};
  const ushort_t* Bbase[3] = {B0, B1, B2};

  f32x4 acc[4][4];
  #pragma unroll
  for (int i = 0; i < 4; i++)
    #pragma unroll
    for (int j = 0; j < 4; j++){ f32x4 z = {0.f, 0.f, 0.f, 0.f}; acc[i][j] = z; }

  const int nk = K >> 5; // K/32
  for (int kt = 0; kt < nk; ++kt){
    __syncthreads();
    #pragma unroll
    for (int s = 0; s < SPLITS; s++){
      #pragma unroll
      for (int i = 0; i < 2; i++){
        int o = i * 4096 + tid * 16;      // byte offset within one 8KB tile
        int rr = o >> 6;                   // row 0..127
        int slot = (o >> 4) & 3;
        int cc = slot ^ ((rr ^ (rr >> 2)) & 3);
        const ushort_t* srcA = Abase[s] + (size_t)(mrow0 + rr) * K + kt * 32 + cc * 8;
        gload16(srcA, (char*)lds + s * 8192 + o);
        const ushort_t* srcB = Bbase[s] + (size_t)(ncol0 + rr) * K + kt * 32 + cc * 8;
        gload16(srcB, (char*)lds + (SPLITS + s) * 8192 + o);
      }
    }
    __syncthreads();

    short8 bf[SPLITS][4];
    #pragma unroll
    for (int s = 0; s < SPLITS; s++){
      #pragma unroll
      for (int ni = 0; ni < 4; ni++){
        int row = wc * 64 + ni * 16 + lr;
        int byt = (SPLITS + s) * 8192 + row * 64 + ((q ^ ((row ^ (row >> 2)) & 3)) * 16);
        bf[s][ni] = *(const short8*)((const char*)lds + byt);
      }
    }
    #pragma unroll
    for (int sa = 0; sa < SPLITS; sa++){
      short8 af[4];
      #pragma unroll
      for (int mi = 0; mi < 4; mi++){
        int row = wr * 64 + mi * 16 + lr;
        int byt = sa * 8192 + row * 64 + ((q ^ ((row ^ (row >> 2)) & 3)) * 16);
        af[mi] = *(const short8*)((const char*)lds + byt);
      }
      #pragma unroll
      for (int sb = 0; sb < SPLITS - sa; sb++){
        #pragma unroll
        for (int mi = 0; mi < 4; mi++)
          #pragma unroll
          for (int ni = 0; ni < 4; ni++)
            acc[mi][ni] = __builtin_amdgcn_mfma_f32_16x16x32_bf16(
                af[mi], bf[sb][ni], acc[mi][ni], 0, 0, 0);
      }
    }
  }

  // epilogue: C element (reg j, lane): row = q*4+j (within frag), col = lr
  if constexpr (EPI == EPI_H){
    #pragma unroll
    for (int mi = 0; mi < 4; mi++){
      #pragma unroll
      for (int ni = 0; ni < 4; ni++){
        int gcol = ncol0 + wc * 64 + ni * 16 + lr;
        float b = bias[gcol];
        #pragma unroll
        for (int j = 0; j < 4; j++){
          int grow = mrow0 + wr * 64 + mi * 16 + q * 4 + j;
          float v = acc[mi][ni][j] + b;
          v = fmaxf(v, 0.0f);
          unsigned short hb = f2bf(v);
          float r1 = v - bf2f(hb);
          unsigned short mb = f2bf(r1);
          float r2 = r1 - bf2f(mb);
          unsigned short lb = f2bf(r2);
          size_t off = (size_t)grow * N + gcol;
          oh[off] = hb; om[off] = mb; ol[off] = lb;
        }
      }
    }
  } else if constexpr (EPI == EPI_NORM){
    #pragma unroll
    for (int mi = 0; mi < 4; mi++){
      float part[4] = {0.f, 0.f, 0.f, 0.f};
      #pragma unroll
      for (int ni = 0; ni < 4; ni++){
        int gcol = ncol0 + wc * 64 + ni * 16 + lr;
        float b = bias[gcol];
        #pragma unroll
        for (int j = 0; j < 4; j++){
          float v = acc[mi][ni][j] + b;
          part[j] += v * v;
        }
      }
      #pragma unroll
      for (int j = 0; j < 4; j++){
        float s = part[j];
        s += __shfl_xor(s, 1); s += __shfl_xor(s, 2);
        s += __shfl_xor(s, 4); s += __shfl_xor(s, 8);
        if (lr == 0){
          int grow = mrow0 + wr * 64 + mi * 16 + q * 4 + j;
          atomicAdd(&outF[grow], s);
        }
      }
    }
  } else {
    #pragma unroll
    for (int mi = 0; mi < 4; mi++)
      #pragma unroll
      for (int ni = 0; ni < 4; ni++)
        #pragma unroll
        for (int j = 0; j < 4; j++){
          int grow = mrow0 + wr * 64 + mi * 16 + q * 4 + j;
          int gcol = ncol0 + wc * 64 + ni * 16 + lr;
          outF[(size_t)grow * N + gcol] = acc[mi][ni][j];
        }
  }
}

// ---------------------------------------------------------------------------
// top-k + softmax + importance/load accumulation. one wave per row.
// ---------------------------------------------------------------------------
__global__ void topk_kernel(const float* __restrict__ r, const float* __restrict__ cvec,
                            const float* __restrict__ norm2,
                            float* __restrict__ out, int* __restrict__ idxout,
                            float* __restrict__ g_imp, int* __restrict__ g_cnt){
  __shared__ float imp_s[64];
  __shared__ int cnt_s[64];
  int tid = threadIdx.x;
  if (tid < 64){ imp_s[tid] = 0.f; cnt_s[tid] = 0; }
  __syncthreads();
  int lane = tid & 63, wid = tid >> 6;
  int gw = blockIdx.x * 4 + wid; // 0..1023
  for (int row = gw; row < T_ROWS; row += 1024){
    float invn = 1.0f / fmaxf(sqrtf(norm2[row]), 1e-12f);
    float cur = (r[(size_t)row * 128 + lane] + cvec[lane]) * invn;
    float vals[9]; int idxs[9];
    #pragma unroll
    for (int it = 0; it < 9; ++it){
      float bv = cur; int bi = lane;
      #pragma unroll
      for (int m = 32; m >= 1; m >>= 1){
        float ov = __shfl_xor(bv, m);
        int oi = __shfl_xor(bi, m);
        if (ov > bv || (ov == bv && oi < bi)){ bv = ov; bi = oi; }
      }
      vals[it] = bv; idxs[it] = bi;
      if (lane == bi) cur = -INFINITY;
    }
    float m0 = vals[0];
    float e[8]; float sum = 0.f;
    #pragma unroll
    for (int i = 0; i < 8; i++){ e[i] = expf(vals[i] - m0); sum += e[i]; }
    float rs = 1.0f / sum;
    if (lane < 8){
      float myS = 0.f; int myI = 0;
      #pragma unroll
      for (int i = 0; i < 8; i++) if (lane == i){ myS = e[i] * rs; myI = idxs[i]; }
      out[(size_t)row * 8 + lane] = (float)myI;
      out[131072 + (size_t)row * 8 + lane] = myS;
      idxout[row * 8 + lane] = myI;
      atomicAdd(&imp_s[myI], myS);
      atomicAdd(&cnt_s[myI], 1);
    }
  }
  __syncthreads();
  if (tid < 64){
    atomicAdd(&g_imp[tid], imp_s[tid]);
    atomicAdd(&g_cnt[tid], cnt_s[tid]);
  }
}

// ---------------------------------------------------------------------------
// balance loss + copy load/importance to out. 64 threads (1 wave).
// ---------------------------------------------------------------------------
__global__ void balance_kernel(const float* __restrict__ imp, const int* __restrict__ cnt,
                               float* __restrict__ out){
  int t = threadIdx.x; // 64
  float vi = imp[t];
  float vl = (float)cnt[t];
  float si = vi, sl = vl;
  #pragma unroll
  for (int m = 1; m < 64; m <<= 1){ si += __shfl_xor(si, m); sl += __shfl_xor(sl, m); }
  float mi = si / 64.f, ml = sl / 64.f;
  float di = vi - mi, dl = vl - ml;
  float qi = di * di, ql = dl * dl;
  #pragma unroll
  for (int m = 1; m < 64; m <<= 1){ qi += __shfl_xor(qi, m); ql += __shfl_xor(ql, m); }
  float vari = qi / 63.f, varl = ql / 63.f;
  float cv2i = vari / (mi * mi + 1e-10f);
  float cv2l = varl / (ml * ml + 1e-10f);
  if (t == 0) out[262144] = 0.01f * (cv2i + cv2l);
  out[262145 + t] = vl;
  out[262209 + t] = vi;
}

// ---------------------------------------------------------------------------
// selected_keys gather: out[row] = kn[idx[row]], 131072 rows x 2048 floats
// (out base is 4B-misaligned for float4 -> use align(4) vectors)
// ---------------------------------------------------------------------------
__global__ void gather_kernel(const int* __restrict__ idx, const float* __restrict__ kn,
                              float* __restrict__ outSel){
  int rowid = blockIdx.x * 4 + (threadIdx.x >> 6);
  int lane = threadIdx.x & 63;
  int e = idx[rowid];
  const float* src = kn + (size_t)e * DIM;
  float* dst = outSel + (size_t)rowid * DIM;
  #pragma unroll
  for (int i = 0; i < 8; i++){
    f4u v = *(const f4u*)(src + lane * 4 + i * 256);
    *(f4u*)(dst + lane * 4 + i * 256) = v;
  }
}

// ===========================================================================
extern "C" void kernel_launch(void* const* d_in, const int* in_sizes, int n_in,
                              void* d_out, int out_size, void* d_ws, size_t ws_size,
                              hipStream_t stream){
  const float* x    = (const float*)d_in[0];
  const float* W1   = (const float*)d_in[1];
  const float* b1   = (const float*)d_in[2];
  const float* W2   = (const float*)d_in[3];
  const float* b2   = (const float*)d_in[4];
  const float* keys = (const float*)d_in[5];
  float* out = (float*)d_out;
  char* ws = (char*)d_ws;

  // ---- ws layout (bytes, all 256-aligned) ----
  const size_t SPLIT_X = 67108864;  // 16384*2048*2
  const size_t SPLIT_W = 8388608;   // 2048*2048*2
  size_t off = 0;
  ushort_t* xh = (ushort_t*)(ws + off); off += SPLIT_X;
  ushort_t* xm = (ushort_t*)(ws + off); off += SPLIT_X;
  ushort_t* xl = (ushort_t*)(ws + off); off += SPLIT_X;
  ushort_t* w1h = (ushort_t*)(ws + off); off += SPLIT_W;
  ushort_t* w1m = (ushort_t*)(ws + off); off += SPLIT_W;
  ushort_t* w1l = (ushort_t*)(ws + off); off += SPLIT_W;
  ushort_t* w2h = (ushort_t*)(ws + off); off += SPLIT_W;
  ushort_t* hh = (ushort_t*)(ws + off); off += SPLIT_X;
  ushort_t* hm = (ushort_t*)(ws + off); off += SPLIT_X;
  ushort_t* hl = (ushort_t*)(ws + off); off += SPLIT_X;
  float* kn = (float*)(ws + off); off += 524288;       // 64*2048*4
  size_t zero_off = off;
  float* Vt = (float*)(ws + off); off += 1048576;      // 128*2048*4  [zeroed]
  float* norm2 = (float*)(ws + off); off += 65536;     // 16384*4     [zeroed]
  float* g_imp = (float*)(ws + off); off += 256;       // [zeroed]
  int*   g_cnt = (int*)(ws + off); off += 256;         // [zeroed]
  size_t zero_len = off - zero_off;
  ushort_t* vth = (ushort_t*)(ws + off); off += 524288; // 128*2048*2
  ushort_t* vtm = (ushort_t*)(ws + off); off += 524288;
  ushort_t* vtl = (ushort_t*)(ws + off); off += 524288;
  float* cv = (float*)(ws + off); off += 256;
  float* r = (float*)(ws + off); off += 8388608;        // 16384*128*4
  int* idxw = (int*)(ws + off); off += 524288;          // 16384*8*4
  (void)ws_size; (void)in_sizes; (void)n_in; (void)out_size;

  hipMemsetAsync(ws + zero_off, 0, zero_len, stream);

  split_kernel<3><<<4096, 256, 0, stream>>>(x, (size_t)33554432, xh, xm, xl);
  split_kernel<3><<<2048, 256, 0, stream>>>(W1, (size_t)4194304, w1h, w1m, w1l);
  split_kernel<1><<<2048, 256, 0, stream>>>(W2, (size_t)4194304, w2h, nullptr, nullptr);
  knorm_kernel<<<64, 256, 0, stream>>>(keys, kn);
  vt_kernel<<<256, 256, 0, stream>>>(W2, kn, Vt);
  cvec_kernel<<<64, 64, 0, stream>>>(b2, kn, cv);
  split_kernel<3><<<256, 256, 0, stream>>>(Vt, (size_t)262144, vth, vtm, vtl);

  // GEMM1: h = relu(x @ W1^T + b1)   grid 128x16
  gemm_bt<3, EPI_H><<<2048, 256, 0, stream>>>(
      xh, xm, xl, w1h, w1m, w1l, 16384, 2048, 2048, 16, b1, nullptr, hh, hm, hl);
  // GEMM2: norm2[t] = || h @ W2^T + b2 ||^2  (atomic)
  gemm_bt<1, EPI_NORM><<<2048, 256, 0, stream>>>(
      hh, nullptr, nullptr, w2h, nullptr, nullptr, 16384, 2048, 2048, 16, b2, norm2,
      nullptr, nullptr, nullptr);
  // rGEMM: r = h @ Vt^T  (N=128 padded)
  gemm_bt<3, EPI_F32><<<128, 256, 0, stream>>>(
      hh, hm, hl, vth, vtm, vtl, 16384, 128, 2048, 1, nullptr, r,
      nullptr, nullptr, nullptr);

  topk_kernel<<<256, 256, 0, stream>>>(r, cv, norm2, out, idxw, g_imp, g_cnt);
  balance_kernel<<<1, 64, 0, stream>>>(g_imp, g_cnt, out);
  gather_kernel<<<32768, 256, 0, stream>>>(idxw, kn, out + 262273);
}